// Round 3
// baseline (279.778 us; speedup 1.0000x reference)
//
#include <hip/hip_runtime.h>
#include <cstdint>
#include <cstddef>

// x[B=32, T=4096, N=256] fp32 -> z same shape.
// Refractory scan: spike at step t iff x>0 and t >= na; then na = t+6.
// Entry state q==k  <=>  first k steps of chunk blocked (na=k). q in [0,5].
#define BB 32
#define TT 4096
#define NN 256
#define CC 128        // chunk length (per-thread scan)
#define PSUB 4        // chunks handled per block (one per 64-thread group)
#define PG 8          // chunk-groups per chain: T / (CC*PSUB) = 8
#define NH 2          // N split into 2 halves -> 512 blocks, 2 blocks/CU
#define HC 128        // channels per half
#define MSG_WORDS 16  // 128 chains * 4-bit state / 8 per u32

__global__ __launch_bounds__(256) void refrac_fused(const float* __restrict__ x,
                                                    float* __restrict__ z,
                                                    uint32_t* __restrict__ msg) {
    const int tid  = threadIdx.x;
    const int half = blockIdx.x & 1;          // N half
    const int b    = (blockIdx.x >> 1) & 31;  // batch
    const int pg   = blockIdx.x >> 6;         // chunk-group (0 dispatched first)
    const int psub = tid >> 6;                // which of 4 chunks in this group
    const int n8   = tid & 63;                // float2 group within the half
    const int p    = pg * PSUB + psub;        // absolute chunk index

    const float2* __restrict__ xv = reinterpret_cast<const float2*>(
        x + ((size_t)b * TT + (size_t)p * CC) * NN + half * HC) + n8;
    // stride per time step: NN/2 = 128 float2

    // --- Phase 1: scan chunk for all 6 entry states; stash sign bits ---
    int na[2][6];
    #pragma unroll
    for (int c = 0; c < 2; ++c)
        #pragma unroll
        for (int e = 0; e < 6; ++e) na[c][e] = e;

    uint32_t bits[2][4];  // [chain][word], 128 bits per chain

    #pragma unroll
    for (int w = 0; w < 4; ++w) {
        uint32_t cur[2] = {0u, 0u};
        for (int jb = 0; jb < 32; jb += 8) {   // dynamic: keeps code size sane
            float2 buf[8];
            #pragma unroll
            for (int u = 0; u < 8; ++u)
                buf[u] = xv[(size_t)(w * 32 + jb + u) * (NN / 2)];
            #pragma unroll
            for (int u = 0; u < 8; ++u) {
                const int j2 = jb + u;         // bit position in word w
                const int j  = w * 32 + j2;    // step within chunk
                const float fv[2] = {buf[u].x, buf[u].y};
                #pragma unroll
                for (int c = 0; c < 2; ++c) {
                    const bool pos = fv[c] > 0.0f;
                    cur[c] |= pos ? (1u << j2) : 0u;
                    #pragma unroll
                    for (int e = 0; e < 6; ++e)
                        if (pos & (j >= na[c][e])) na[c][e] = j + 6;
                }
            }
        }
        #pragma unroll
        for (int c = 0; c < 2; ++c) bits[c][w] = cur[c];
    }

    // Pack exit table (6 nibbles) per chain into LDS.
    __shared__ uint32_t tbl_lds[PSUB][HC];
    __shared__ uint8_t  ent_lds[PSUB][HC];
    __shared__ uint8_t  sout_lds[HC];

    #pragma unroll
    for (int c = 0; c < 2; ++c) {
        uint32_t tbl = 0;
        #pragma unroll
        for (int e = 0; e < 6; ++e) {
            int q = na[c][e] - CC;
            q = q > 0 ? q : 0;                 // exit state in [0,5]
            tbl |= (uint32_t)q << (4 * e);
        }
        tbl_lds[psub][n8 * 2 + c] = tbl;
    }
    __syncthreads();

    // --- Phase 2: resolve true entry states (thread n handles chain n) ---
    if (tid < HC) {
        const int n = tid;
        int e = 0;
        if (pg > 0) {
            const uint32_t* inw = msg +
                (((size_t)b * PG + (pg - 1)) * NH + half) * MSG_WORDS + (n >> 3);
            uint32_t wv;
            // nibble bit3 set (poison 0xA) => not ready; states <=5 are valid
            while ((wv = __hip_atomic_load(inw, __ATOMIC_RELAXED,
                                           __HIP_MEMORY_SCOPE_AGENT)) & 0x88888888u)
                __builtin_amdgcn_s_sleep(1);
            e = (int)((wv >> ((n & 7) * 4)) & 0xFu);
        }
        #pragma unroll
        for (int s = 0; s < PSUB; ++s) {
            ent_lds[s][n] = (uint8_t)e;
            e = (int)((tbl_lds[s][n] >> (4 * e)) & 0xFu);
        }
        sout_lds[n] = (uint8_t)e;              // exit of last chunk in group
    }
    __syncthreads();

    if (pg < PG - 1 && tid < MSG_WORDS) {
        uint32_t wv = 0;
        #pragma unroll
        for (int k = 0; k < 8; ++k)
            wv |= (uint32_t)sout_lds[tid * 8 + k] << (4 * k);
        __hip_atomic_store(msg + (((size_t)b * PG + pg) * NH + half) * MSG_WORDS + tid,
                           wv, __ATOMIC_RELAXED, __HIP_MEMORY_SCOPE_AGENT);
    }

    // --- Phase 3: emit z from register bits + resolved entry ---
    float2* __restrict__ zv = reinterpret_cast<float2*>(
        z + ((size_t)b * TT + (size_t)p * CC) * NN + half * HC) + n8;

    int ea[2];
    #pragma unroll
    for (int c = 0; c < 2; ++c) ea[c] = (int)ent_lds[psub][n8 * 2 + c];

    #pragma unroll
    for (int w = 0; w < 4; ++w) {
        const uint32_t bw[2] = {bits[0][w], bits[1][w]};
        for (int j2 = 0; j2 < 32; ++j2) {
            const int j = w * 32 + j2;
            float o[2];
            #pragma unroll
            for (int c = 0; c < 2; ++c) {
                const bool sp = (((bw[c] >> j2) & 1u) != 0u) & (j >= ea[c]);
                if (sp) ea[c] = j + 6;
                o[c] = sp ? 1.0f : 0.0f;
            }
            zv[(size_t)j * (NN / 2)] = make_float2(o[0], o[1]);
        }
    }
}

extern "C" void kernel_launch(void* const* d_in, const int* in_sizes, int n_in,
                              void* d_out, int out_size, void* d_ws, size_t ws_size,
                              hipStream_t stream) {
    const float* x = (const float*)d_in[0];
    float* z = (float*)d_out;
    uint32_t* msg = (uint32_t*)d_ws;

    // Deterministic "not ready" poison for the message area each call.
    hipMemsetAsync(d_ws, 0xAA,
                   (size_t)BB * PG * NH * MSG_WORDS * sizeof(uint32_t), stream);

    refrac_fused<<<dim3(BB * PG * NH), 256, 0, stream>>>(x, z, msg);
}